// Round 1
// baseline (480.056 us; speedup 1.0000x reference)
//
#include <hip/hip_runtime.h>

// Trilinear interpolation of 2M points into a 128x128x128x16 fp32 grid.
// v2: bucket points by 8^3-voxel region (4096 buckets) so each workgroup's
// gathers hit a ~47 KB region (L1/L2-resident) instead of random access
// over the full 134 MB grid.
//
// Pass 1 (scatter): bin points into per-bucket record arrays via atomic
//   cursors (capacity 640 vs Poisson mean 488; overflow -> direct compute,
//   statistically never taken but correctness-guaranteed).
// Pass 2 (interp): one block per bucket; 4 lanes per point (float4 per lane,
//   16 channels); scattered 64B output writes preserve original point order.

#define DD 128
#define HH 128
#define WW 128
#define NBX 16                     // buckets per dimension (8^3 voxels each)
#define NB (NBX * NBX * NBX)       // 4096 buckets
#define CAP 640                    // records per bucket (mean 488, +6.9 sigma)
#define CUR_STRIDE 16              // cursor padding: 64B apart -> no line contention

typedef float fvec4 __attribute__((ext_vector_type(4)));

__device__ __forceinline__ float4 lerp4(float4 a, float4 b, float t) {
    return make_float4(fmaf(b.x - a.x, t, a.x),
                       fmaf(b.y - a.y, t, a.y),
                       fmaf(b.z - a.z, t, a.z),
                       fmaf(b.w - a.w, t, a.w));
}

__device__ __forceinline__ int clampi(int v, int lo, int hi) {
    return min(max(v, lo), hi);
}

// Exact same op order as the verified v1 kernel (bit-identical results).
__device__ __forceinline__ float4 trilerp_point(const float4* __restrict__ values,
                                                float x, float y, float z, int c4) {
    float fx = floorf(x), fy = floorf(y), fz = floorf(z);
    int x0 = clampi((int)fx, 0, DD - 1);
    int y0 = clampi((int)fy, 0, HH - 1);
    int z0 = clampi((int)fz, 0, WW - 1);
    int x1 = min(x0 + 1, DD - 1);
    int y1 = min(y0 + 1, HH - 1);
    int z1 = min(z0 + 1, WW - 1);

    float xd = x - (float)x0;
    float yd = y - (float)y0;
    float zd = z - (float)z0;

    // float4 index: (((xi*128 + yi)*128 + zi) * 4) + c4
    #define VIDX(xi, yi, zi) ((((((xi) << 7) + (yi)) << 7) + (zi)) * 4 + c4)
    float4 c000 = values[VIDX(x0, y0, z0)];
    float4 c001 = values[VIDX(x0, y0, z1)];
    float4 c010 = values[VIDX(x0, y1, z0)];
    float4 c011 = values[VIDX(x0, y1, z1)];
    float4 c100 = values[VIDX(x1, y0, z0)];
    float4 c101 = values[VIDX(x1, y0, z1)];
    float4 c110 = values[VIDX(x1, y1, z0)];
    float4 c111 = values[VIDX(x1, y1, z1)];
    #undef VIDX

    float4 c00 = lerp4(c000, c100, xd);
    float4 c01 = lerp4(c001, c101, xd);
    float4 c10 = lerp4(c010, c110, xd);
    float4 c11 = lerp4(c011, c111, xd);
    float4 c0  = lerp4(c00, c10, yd);
    float4 c1  = lerp4(c01, c11, yd);
    return lerp4(c0, c1, zd);
}

// ---------------- Pass 1: bin points into bucket record arrays ----------------
__global__ __launch_bounds__(256) void scatter_kernel(
    const float* __restrict__ points,
    unsigned* __restrict__ cursors,
    float4* __restrict__ recs,
    const float4* __restrict__ values,   // only for the (never-taken) overflow path
    float4* __restrict__ out,
    int n_points)
{
    int p = blockIdx.x * blockDim.x + threadIdx.x;
    if (p >= n_points) return;

    float x = points[p * 3 + 0] * 20.0f;   // 1/VOXEL_SIZE = 20
    float y = points[p * 3 + 1] * 20.0f;
    float z = points[p * 3 + 2] * 20.0f;

    int bx = clampi((int)floorf(x), 0, DD - 1) >> 3;
    int by = clampi((int)floorf(y), 0, HH - 1) >> 3;
    int bz = clampi((int)floorf(z), 0, WW - 1) >> 3;
    int b = (bx * NBX + by) * NBX + bz;

    unsigned pos = atomicAdd(&cursors[b * CUR_STRIDE], 1u);
    if (pos < CAP) {
        float4 r = make_float4(x, y, z, __uint_as_float((unsigned)p));
        recs[(unsigned)b * CAP + pos] = r;
    } else {
        // Overflow (P ~ 1e-11 per bucket): compute this point directly.
        #pragma unroll
        for (int c = 0; c < 4; ++c)
            out[p * 4 + c] = trilerp_point(values, x, y, z, c);
    }
}

// ---------------- Pass 2: one block per bucket ----------------
__global__ __launch_bounds__(256) void interp_kernel(
    const float4* __restrict__ recs,
    const unsigned* __restrict__ cursors,
    const float4* __restrict__ values,
    float4* __restrict__ out)
{
    int b = blockIdx.x;
    unsigned cnt = cursors[b * CUR_STRIDE];
    if (cnt > CAP) cnt = CAP;
    unsigned base = (unsigned)b * CAP;
    int c4 = threadIdx.x & 3;

    for (unsigned j = threadIdx.x >> 2; j < cnt; j += 64) {
        float4 r = recs[base + j];          // 4 lanes share one record (coalesced)
        float4 res = trilerp_point(values, r.x, r.y, r.z, c4);
        unsigned idx = __float_as_uint(r.w);
        // Scattered 64B write (order-preserving); nontemporal keeps L2 for values.
        __builtin_nontemporal_store(*(fvec4*)&res, (fvec4*)(out + ((size_t)idx * 4 + c4)));
    }
}

// ---------------- Fallback: v1 direct kernel (if workspace too small) ----------------
__global__ __launch_bounds__(256) void trilerp_kernel(
    const float* __restrict__ points,
    const float4* __restrict__ values,
    float4* __restrict__ out,
    int n_points)
{
    int t = blockIdx.x * blockDim.x + threadIdx.x;
    int p = t >> 2;
    int c4 = t & 3;
    if (p >= n_points) return;

    float x = points[p * 3 + 0] * 20.0f;
    float y = points[p * 3 + 1] * 20.0f;
    float z = points[p * 3 + 2] * 20.0f;
    out[t] = trilerp_point(values, x, y, z, c4);
}

extern "C" void kernel_launch(void* const* d_in, const int* in_sizes, int n_in,
                              void* d_out, int out_size, void* d_ws, size_t ws_size,
                              hipStream_t stream) {
    const float* points = (const float*)d_in[0];
    const float4* values = (const float4*)d_in[1];
    float4* out = (float4*)d_out;

    int n_points = in_sizes[0] / 3;

    const size_t cursors_bytes = (size_t)NB * CUR_STRIDE * sizeof(unsigned);   // 256 KB
    const size_t recs_bytes = (size_t)NB * CAP * sizeof(float4);               // ~42 MB
    const size_t required = cursors_bytes + recs_bytes;

    if (d_ws != nullptr && ws_size >= required) {
        unsigned* cursors = (unsigned*)d_ws;
        float4* recs = (float4*)((char*)d_ws + cursors_bytes);

        hipMemsetAsync(cursors, 0, cursors_bytes, stream);

        int blocks = (n_points + 255) / 256;
        scatter_kernel<<<blocks, 256, 0, stream>>>(points, cursors, recs, values, out, n_points);
        interp_kernel<<<NB, 256, 0, stream>>>(recs, cursors, values, out);
    } else {
        int total_threads = n_points * 4;
        int blocks = (total_threads + 255) / 256;
        trilerp_kernel<<<blocks, 256, 0, stream>>>(points, values, out, n_points);
    }
}

// Round 2
// 439.708 us; speedup vs baseline: 1.0918x; 1.0918x over previous
//
#include <hip/hip_runtime.h>

// Trilinear interpolation of 2M points into a 128x128x128x16 fp32 grid.
// v3: bucket points by 8^3-voxel region (4096 buckets).
//  - Scatter: 4-way partitioned record arrays (cuts cross-XCD partial-line
//    sharing) + nontemporal 16B record stores (no L2 write-allocate RMW).
//  - Interp: stage the bucket's 9x9x9-voxel halo (46.6 KB) into LDS once,
//    then all 8 corner gathers are ds_read_b128 instead of scattered global.
// Results bit-identical to v1 (same op order, same values).

#define DD 128
#define HH 128
#define WW 128
#define NBX 16                     // buckets per dimension (8^3 voxels each)
#define NB (NBX * NBX * NBX)       // 4096 buckets
#define NPART 4                    // record partitions (by blockIdx&3 ~ XCD pairs)
#define CAP2 152                   // records per sub-bucket (mean 122, +2.7 sigma;
                                   // overflow -> direct compute, correctness-safe)
#define CUR_STRIDE 16              // cursor padding: 64B apart

typedef float fvec4 __attribute__((ext_vector_type(4)));

__device__ __forceinline__ float4 lerp4(float4 a, float4 b, float t) {
    return make_float4(fmaf(b.x - a.x, t, a.x),
                       fmaf(b.y - a.y, t, a.y),
                       fmaf(b.z - a.z, t, a.z),
                       fmaf(b.w - a.w, t, a.w));
}

__device__ __forceinline__ int clampi(int v, int lo, int hi) {
    return min(max(v, lo), hi);
}

// Direct (global-gather) path — identical to verified v1.
__device__ __forceinline__ float4 trilerp_point(const float4* __restrict__ values,
                                                float x, float y, float z, int c4) {
    float fx = floorf(x), fy = floorf(y), fz = floorf(z);
    int x0 = clampi((int)fx, 0, DD - 1);
    int y0 = clampi((int)fy, 0, HH - 1);
    int z0 = clampi((int)fz, 0, WW - 1);
    int x1 = min(x0 + 1, DD - 1);
    int y1 = min(y0 + 1, HH - 1);
    int z1 = min(z0 + 1, WW - 1);

    float xd = x - (float)x0;
    float yd = y - (float)y0;
    float zd = z - (float)z0;

    #define VIDX(xi, yi, zi) ((((((xi) << 7) + (yi)) << 7) + (zi)) * 4 + c4)
    float4 c000 = values[VIDX(x0, y0, z0)];
    float4 c001 = values[VIDX(x0, y0, z1)];
    float4 c010 = values[VIDX(x0, y1, z0)];
    float4 c011 = values[VIDX(x0, y1, z1)];
    float4 c100 = values[VIDX(x1, y0, z0)];
    float4 c101 = values[VIDX(x1, y0, z1)];
    float4 c110 = values[VIDX(x1, y1, z0)];
    float4 c111 = values[VIDX(x1, y1, z1)];
    #undef VIDX

    float4 c00 = lerp4(c000, c100, xd);
    float4 c01 = lerp4(c001, c101, xd);
    float4 c10 = lerp4(c010, c110, xd);
    float4 c11 = lerp4(c011, c111, xd);
    float4 c0  = lerp4(c00, c10, yd);
    float4 c1  = lerp4(c01, c11, yd);
    return lerp4(c0, c1, zd);
}

// ---------------- Pass 1: bin points into partitioned bucket arrays ----------------
__global__ __launch_bounds__(256) void scatter_kernel(
    const float* __restrict__ points,
    unsigned* __restrict__ cursors,
    float4* __restrict__ recs,
    const float4* __restrict__ values,   // for the rare overflow path
    float4* __restrict__ out,
    int n_points)
{
    int p = blockIdx.x * blockDim.x + threadIdx.x;
    if (p >= n_points) return;
    int part = blockIdx.x & (NPART - 1);

    float x = points[p * 3 + 0] * 20.0f;   // 1/VOXEL_SIZE = 20
    float y = points[p * 3 + 1] * 20.0f;
    float z = points[p * 3 + 2] * 20.0f;

    int bx = clampi((int)floorf(x), 0, DD - 1) >> 3;
    int by = clampi((int)floorf(y), 0, HH - 1) >> 3;
    int bz = clampi((int)floorf(z), 0, WW - 1) >> 3;
    int sb = (part * NB) + ((bx * NBX + by) * NBX + bz);

    unsigned pos = atomicAdd(&cursors[sb * CUR_STRIDE], 1u);
    if (pos < CAP2) {
        fvec4 r = { x, y, z, __uint_as_float((unsigned)p) };
        __builtin_nontemporal_store(r, (fvec4*)(recs + (size_t)sb * CAP2 + pos));
    } else {
        // Overflow (rare, few hundred points worst case): compute directly.
        #pragma unroll
        for (int c = 0; c < 4; ++c)
            out[p * 4 + c] = trilerp_point(values, x, y, z, c);
    }
}

// ---------------- Pass 2: one block per bucket, LDS-staged halo ----------------
__global__ __launch_bounds__(256) void interp_kernel(
    const float4* __restrict__ recs,
    const unsigned* __restrict__ cursors,
    const float4* __restrict__ values,
    float4* __restrict__ out)
{
    __shared__ float4 sv[9 * 9 * 9 * 4];   // 46,656 B halo: voxel(i,j,k) ch-quad c

    int b = blockIdx.x;
    int bz = b & 15, by = (b >> 4) & 15, bx = b >> 8;
    int X0 = bx << 3, Y0 = by << 3, Z0 = bz << 3;

    // Stage 9x9x9 voxels (clamped at grid edge), coalesced along z/c.
    for (int e = threadIdx.x; e < 9 * 9 * 9 * 4; e += 256) {
        int v = e >> 2, c = e & 3;
        int i = v / 81;
        int r = v - i * 81;
        int j = r / 9;
        int k = r - j * 9;
        int gx = min(X0 + i, DD - 1);
        int gy = min(Y0 + j, HH - 1);
        int gz = min(Z0 + k, WW - 1);
        sv[e] = values[((((gx << 7) + gy) << 7) + gz) * 4 + c];
    }
    __syncthreads();

    int c4 = threadIdx.x & 3;

    #define SIDX(i, j, k) (((((i) * 9) + (j)) * 9 + (k)) * 4 + c4)
    for (int part = 0; part < NPART; ++part) {
        int sb = part * NB + b;
        unsigned cnt = cursors[sb * CUR_STRIDE];
        if (cnt > CAP2) cnt = CAP2;
        const float4* rp = recs + (size_t)sb * CAP2;

        for (unsigned j = threadIdx.x >> 2; j < cnt; j += 64) {
            float4 r = rp[j];                 // 4 lanes share one record
            float x = r.x, y = r.y, z = r.z;

            float fx = floorf(x), fy = floorf(y), fz = floorf(z);
            int x0 = clampi((int)fx, 0, DD - 1);
            int y0 = clampi((int)fy, 0, HH - 1);
            int z0 = clampi((int)fz, 0, WW - 1);
            float xd = x - (float)x0;
            float yd = y - (float)y0;
            float zd = z - (float)z0;

            int xl = x0 - X0, yl = y0 - Y0, zl = z0 - Z0;   // 0..7
            // Halo voxel [8] == clamped duplicate, so +1 is always valid and
            // matches values[min(g+1, 127)] exactly.
            float4 c000 = sv[SIDX(xl,     yl,     zl    )];
            float4 c001 = sv[SIDX(xl,     yl,     zl + 1)];
            float4 c010 = sv[SIDX(xl,     yl + 1, zl    )];
            float4 c011 = sv[SIDX(xl,     yl + 1, zl + 1)];
            float4 c100 = sv[SIDX(xl + 1, yl,     zl    )];
            float4 c101 = sv[SIDX(xl + 1, yl,     zl + 1)];
            float4 c110 = sv[SIDX(xl + 1, yl + 1, zl    )];
            float4 c111 = sv[SIDX(xl + 1, yl + 1, zl + 1)];

            float4 c00 = lerp4(c000, c100, xd);
            float4 c01 = lerp4(c001, c101, xd);
            float4 c10 = lerp4(c010, c110, xd);
            float4 c11 = lerp4(c011, c111, xd);
            float4 c0  = lerp4(c00, c10, yd);
            float4 c1  = lerp4(c01, c11, yd);
            float4 res = lerp4(c0, c1, zd);

            unsigned idx = __float_as_uint(r.w);
            __builtin_nontemporal_store(*(fvec4*)&res, (fvec4*)(out + ((size_t)idx * 4 + c4)));
        }
    }
    #undef SIDX
}

// ---------------- Fallback: v1 direct kernel (if workspace too small) ----------------
__global__ __launch_bounds__(256) void trilerp_kernel(
    const float* __restrict__ points,
    const float4* __restrict__ values,
    float4* __restrict__ out,
    int n_points)
{
    int t = blockIdx.x * blockDim.x + threadIdx.x;
    int p = t >> 2;
    int c4 = t & 3;
    if (p >= n_points) return;

    float x = points[p * 3 + 0] * 20.0f;
    float y = points[p * 3 + 1] * 20.0f;
    float z = points[p * 3 + 2] * 20.0f;
    out[t] = trilerp_point(values, x, y, z, c4);
}

extern "C" void kernel_launch(void* const* d_in, const int* in_sizes, int n_in,
                              void* d_out, int out_size, void* d_ws, size_t ws_size,
                              hipStream_t stream) {
    const float* points = (const float*)d_in[0];
    const float4* values = (const float4*)d_in[1];
    float4* out = (float4*)d_out;

    int n_points = in_sizes[0] / 3;

    const size_t cursors_bytes = (size_t)NPART * NB * CUR_STRIDE * sizeof(unsigned); // 1 MB
    const size_t recs_bytes = (size_t)NPART * NB * CAP2 * sizeof(float4);            // ~39.8 MB
    const size_t required = cursors_bytes + recs_bytes;                              // ~40.9 MB

    if (d_ws != nullptr && ws_size >= required) {
        unsigned* cursors = (unsigned*)d_ws;
        float4* recs = (float4*)((char*)d_ws + cursors_bytes);

        hipMemsetAsync(cursors, 0, cursors_bytes, stream);

        int blocks = (n_points + 255) / 256;
        scatter_kernel<<<blocks, 256, 0, stream>>>(points, cursors, recs, values, out, n_points);
        interp_kernel<<<NB, 256, 0, stream>>>(recs, cursors, values, out);
    } else {
        int total_threads = n_points * 4;
        int blocks = (total_threads + 255) / 256;
        trilerp_kernel<<<blocks, 256, 0, stream>>>(points, values, out, n_points);
    }
}

// Round 3
// 417.827 us; speedup vs baseline: 1.1489x; 1.0524x over previous
//
#include <hip/hip_runtime.h>

// Trilinear interpolation of 2M points into a 128x128x128x16 fp32 grid.
// v4: hierarchical LDS-aggregated binning (64 coarse -> 64 fine each),
// so bucket records are written to HBM in contiguous >=512B chunks instead
// of 2M random 16B NT stores (v3's scatter was 4x write-amplified, 155us).
// Interp pass (LDS-staged 9^3 halo) unchanged from v3 - it was the winner.
// Results bit-identical to v1 (same op order everywhere).

#define DD 128
#define NBX 16                      // fine buckets per dim (8^3 voxels)
#define NB  (NBX * NBX * NBX)       // 4096 fine buckets
#define NCX 4                       // coarse buckets per dim (32^3 voxels)
#define NC  (NCX * NCX * NCX)       // 64 coarse buckets
#define NFPC 64                     // fine buckets per coarse (4^3)
#define CAPC 33000                  // coarse region capacity (mean 31250, +10 sigma)
#define CAPF 560                    // fine region capacity (mean 488, +3.2 sigma)
#define CAPL 48                     // LDS staging records per bucket
#define FLUSH_T 32                  // flush threshold (>=512B per flush)
#define CCUR_STRIDE 16              // coarse cursor padding (64B)
#define FCUR_STRIDE 4               // fine cursor padding (16B)
#define SCAT_BLOCKS 512

typedef float fvec4 __attribute__((ext_vector_type(4)));

__device__ __forceinline__ float4 lerp4(float4 a, float4 b, float t) {
    return make_float4(fmaf(b.x - a.x, t, a.x),
                       fmaf(b.y - a.y, t, a.y),
                       fmaf(b.z - a.z, t, a.z),
                       fmaf(b.w - a.w, t, a.w));
}

__device__ __forceinline__ int clampi(int v, int lo, int hi) {
    return min(max(v, lo), hi);
}

// Direct (global-gather) path - identical op order to verified v1.
__device__ __forceinline__ float4 trilerp_point(const float4* __restrict__ values,
                                                float x, float y, float z, int c4) {
    float fx = floorf(x), fy = floorf(y), fz = floorf(z);
    int x0 = clampi((int)fx, 0, DD - 1);
    int y0 = clampi((int)fy, 0, DD - 1);
    int z0 = clampi((int)fz, 0, DD - 1);
    int x1 = min(x0 + 1, DD - 1);
    int y1 = min(y0 + 1, DD - 1);
    int z1 = min(z0 + 1, DD - 1);

    float xd = x - (float)x0;
    float yd = y - (float)y0;
    float zd = z - (float)z0;

    #define VIDX(xi, yi, zi) ((((((xi) << 7) + (yi)) << 7) + (zi)) * 4 + c4)
    float4 c000 = values[VIDX(x0, y0, z0)];
    float4 c001 = values[VIDX(x0, y0, z1)];
    float4 c010 = values[VIDX(x0, y1, z0)];
    float4 c011 = values[VIDX(x0, y1, z1)];
    float4 c100 = values[VIDX(x1, y0, z0)];
    float4 c101 = values[VIDX(x1, y0, z1)];
    float4 c110 = values[VIDX(x1, y1, z0)];
    float4 c111 = values[VIDX(x1, y1, z1)];
    #undef VIDX

    float4 c00 = lerp4(c000, c100, xd);
    float4 c01 = lerp4(c001, c101, xd);
    float4 c10 = lerp4(c010, c110, xd);
    float4 c11 = lerp4(c011, c111, xd);
    float4 c0  = lerp4(c00, c10, yd);
    float4 c1  = lerp4(c01, c11, yd);
    return lerp4(c0, c1, zd);
}

__device__ __forceinline__ void write_point_direct(const float4* __restrict__ values,
                                                   float4* __restrict__ out,
                                                   float x, float y, float z, unsigned p) {
    #pragma unroll
    for (int c = 0; c < 4; ++c)
        out[(size_t)p * 4 + c] = trilerp_point(values, x, y, z, c);
}

// ---------------- Pass 1a: coarse binning (64 buckets), LDS-aggregated ----------------
__global__ __launch_bounds__(256) void coarse_scatter(
    const float* __restrict__ points,
    unsigned* __restrict__ ccur,
    float4* __restrict__ crecs,
    const float4* __restrict__ values,
    float4* __restrict__ out,
    int n_points)
{
    __shared__ float4 stage[NC * CAPL];       // 49152 B
    __shared__ unsigned scnt[NC];

    for (int i = threadIdx.x; i < NC; i += 256) scnt[i] = 0;
    __syncthreads();

    int per = (n_points + SCAT_BLOCKS - 1) / SCAT_BLOCKS;
    int lo = blockIdx.x * per;
    int hi = min(lo + per, n_points);
    int lane = threadIdx.x & 63;
    int wid  = threadIdx.x >> 6;

    for (int base = lo; base < hi; base += 256) {
        int p = base + threadIdx.x;
        if (p < hi) {
            float x = points[p * 3 + 0] * 20.0f;   // 1/VOXEL_SIZE
            float y = points[p * 3 + 1] * 20.0f;
            float z = points[p * 3 + 2] * 20.0f;
            int cx = clampi((int)floorf(x), 0, DD - 1) >> 5;
            int cy = clampi((int)floorf(y), 0, DD - 1) >> 5;
            int cz = clampi((int)floorf(z), 0, DD - 1) >> 5;
            int c = (cx * NCX + cy) * NCX + cz;
            unsigned pos = atomicAdd(&scnt[c], 1u);
            if (pos < CAPL) {
                stage[c * CAPL + pos] = make_float4(x, y, z, __uint_as_float((unsigned)p));
            } else {
                // LDS stage overflow (statistically ~never): single global record
                unsigned g = atomicAdd(&ccur[c * CCUR_STRIDE], 1u);
                if (g < CAPC) {
                    fvec4 r = { x, y, z, __uint_as_float((unsigned)p) };
                    __builtin_nontemporal_store(r, (fvec4*)(crecs + (size_t)c * CAPC + g));
                } else {
                    write_point_direct(values, out, x, y, z, (unsigned)p);
                }
            }
        }
        __syncthreads();
        // Flush buckets that reached the threshold; one wave per 16 buckets.
        for (int cb = wid * 16; cb < wid * 16 + 16; ++cb) {
            unsigned cnt = scnt[cb];
            if (cnt >= FLUSH_T) {
                unsigned wcnt = cnt < CAPL ? cnt : (unsigned)CAPL;
                unsigned gb = 0;
                if (lane == 0) gb = atomicAdd(&ccur[cb * CCUR_STRIDE], wcnt);
                gb = __shfl(gb, 0);
                if (lane < (int)wcnt) {
                    float4 r = stage[cb * CAPL + lane];
                    unsigned g = gb + (unsigned)lane;
                    if (g < CAPC)
                        __builtin_nontemporal_store(*(fvec4*)&r, (fvec4*)(crecs + (size_t)cb * CAPC + g));
                    else
                        write_point_direct(values, out, r.x, r.y, r.z, __float_as_uint(r.w));
                }
                if (lane == 0) scnt[cb] = 0;
            }
        }
        __syncthreads();
    }
    // Final flush (any residue).
    for (int cb = wid * 16; cb < wid * 16 + 16; ++cb) {
        unsigned cnt = scnt[cb];
        if (cnt > 0) {
            unsigned wcnt = cnt < CAPL ? cnt : (unsigned)CAPL;
            unsigned gb = 0;
            if (lane == 0) gb = atomicAdd(&ccur[cb * CCUR_STRIDE], wcnt);
            gb = __shfl(gb, 0);
            if (lane < (int)wcnt) {
                float4 r = stage[cb * CAPL + lane];
                unsigned g = gb + (unsigned)lane;
                if (g < CAPC)
                    __builtin_nontemporal_store(*(fvec4*)&r, (fvec4*)(crecs + (size_t)cb * CAPC + g));
                else
                    write_point_direct(values, out, r.x, r.y, r.z, __float_as_uint(r.w));
            }
        }
    }
}

// ---------------- Pass 1b: refine each coarse bucket into 64 fine buckets ----------------
__global__ __launch_bounds__(256) void fine_scatter(
    const float4* __restrict__ crecs,
    const unsigned* __restrict__ ccur,
    unsigned* __restrict__ fcur,
    float4* __restrict__ frecs,
    const float4* __restrict__ values,
    float4* __restrict__ out)
{
    __shared__ float4 stage[NFPC * CAPL];
    __shared__ unsigned scnt[NFPC];

    for (int i = threadIdx.x; i < NFPC; i += 256) scnt[i] = 0;
    __syncthreads();

    int c   = blockIdx.x >> 3;          // coarse bucket, 8 blocks each
    int sub = blockIdx.x & 7;
    int cx = c >> 4, cy = (c >> 2) & 3, cz = c & 3;
    unsigned total = ccur[c * CCUR_STRIDE];
    if (total > CAPC) total = CAPC;
    unsigned slo = (unsigned)(((unsigned long long)total * (unsigned)sub) >> 3);
    unsigned shi = (unsigned)(((unsigned long long)total * (unsigned)(sub + 1)) >> 3);
    const float4* src = crecs + (size_t)c * CAPC;
    int lane = threadIdx.x & 63;
    int wid  = threadIdx.x >> 6;

    for (unsigned base = slo; base < shi; base += 256) {
        unsigned i = base + threadIdx.x;
        if (i < shi) {
            float4 r = src[i];
            int fx = clampi((int)floorf(r.x), 0, DD - 1) >> 3;
            int fy = clampi((int)floorf(r.y), 0, DD - 1) >> 3;
            int fz = clampi((int)floorf(r.z), 0, DD - 1) >> 3;
            int lf = ((fx & 3) * 4 + (fy & 3)) * 4 + (fz & 3);
            unsigned pos = atomicAdd(&scnt[lf], 1u);
            if (pos < CAPL) {
                stage[lf * CAPL + pos] = r;
            } else {
                int fb = (fx * NBX + fy) * NBX + fz;
                unsigned g = atomicAdd(&fcur[fb * FCUR_STRIDE], 1u);
                if (g < CAPF)
                    __builtin_nontemporal_store(*(fvec4*)&r, (fvec4*)(frecs + (size_t)fb * CAPF + g));
                else
                    write_point_direct(values, out, r.x, r.y, r.z, __float_as_uint(r.w));
            }
        }
        __syncthreads();
        for (int lb = wid * 16; lb < wid * 16 + 16; ++lb) {
            unsigned cnt = scnt[lb];
            if (cnt >= FLUSH_T) {
                unsigned wcnt = cnt < CAPL ? cnt : (unsigned)CAPL;
                int fx = cx * 4 + (lb >> 4);
                int fy = cy * 4 + ((lb >> 2) & 3);
                int fz = cz * 4 + (lb & 3);
                int fb = (fx * NBX + fy) * NBX + fz;
                unsigned gb = 0;
                if (lane == 0) gb = atomicAdd(&fcur[fb * FCUR_STRIDE], wcnt);
                gb = __shfl(gb, 0);
                if (lane < (int)wcnt) {
                    float4 r = stage[lb * CAPL + lane];
                    unsigned g = gb + (unsigned)lane;
                    if (g < CAPF)
                        __builtin_nontemporal_store(*(fvec4*)&r, (fvec4*)(frecs + (size_t)fb * CAPF + g));
                    else
                        write_point_direct(values, out, r.x, r.y, r.z, __float_as_uint(r.w));
                }
                if (lane == 0) scnt[lb] = 0;
            }
        }
        __syncthreads();
    }
    // Final flush.
    for (int lb = wid * 16; lb < wid * 16 + 16; ++lb) {
        unsigned cnt = scnt[lb];
        if (cnt > 0) {
            unsigned wcnt = cnt < CAPL ? cnt : (unsigned)CAPL;
            int fx = cx * 4 + (lb >> 4);
            int fy = cy * 4 + ((lb >> 2) & 3);
            int fz = cz * 4 + (lb & 3);
            int fb = (fx * NBX + fy) * NBX + fz;
            unsigned gb = 0;
            if (lane == 0) gb = atomicAdd(&fcur[fb * FCUR_STRIDE], wcnt);
            gb = __shfl(gb, 0);
            if (lane < (int)wcnt) {
                float4 r = stage[lb * CAPL + lane];
                unsigned g = gb + (unsigned)lane;
                if (g < CAPF)
                    __builtin_nontemporal_store(*(fvec4*)&r, (fvec4*)(frecs + (size_t)fb * CAPF + g));
                else
                    write_point_direct(values, out, r.x, r.y, r.z, __float_as_uint(r.w));
            }
        }
    }
}

// ---------------- Pass 2: one block per fine bucket, LDS-staged halo ----------------
__global__ __launch_bounds__(256) void interp_kernel(
    const float4* __restrict__ recs,
    const unsigned* __restrict__ fcur,
    const float4* __restrict__ values,
    float4* __restrict__ out)
{
    __shared__ float4 sv[9 * 9 * 9 * 4];   // 46,656 B halo

    int b = blockIdx.x;
    int bz = b & 15, by = (b >> 4) & 15, bx = b >> 8;
    int X0 = bx << 3, Y0 = by << 3, Z0 = bz << 3;

    for (int e = threadIdx.x; e < 9 * 9 * 9 * 4; e += 256) {
        int v = e >> 2, cc = e & 3;
        int i = v / 81;
        int rr = v - i * 81;
        int j = rr / 9;
        int k = rr - j * 9;
        int gx = min(X0 + i, DD - 1);
        int gy = min(Y0 + j, DD - 1);
        int gz = min(Z0 + k, DD - 1);
        sv[e] = values[((((gx << 7) + gy) << 7) + gz) * 4 + cc];
    }
    __syncthreads();

    int c4 = threadIdx.x & 3;
    unsigned cnt = fcur[b * FCUR_STRIDE];
    if (cnt > CAPF) cnt = CAPF;
    const float4* rp = recs + (size_t)b * CAPF;

    #define SIDX(i, j, k) (((((i) * 9) + (j)) * 9 + (k)) * 4 + c4)
    for (unsigned j = threadIdx.x >> 2; j < cnt; j += 64) {
        float4 r = rp[j];
        float x = r.x, y = r.y, z = r.z;

        float fx = floorf(x), fy = floorf(y), fz = floorf(z);
        int x0 = clampi((int)fx, 0, DD - 1);
        int y0 = clampi((int)fy, 0, DD - 1);
        int z0 = clampi((int)fz, 0, DD - 1);
        float xd = x - (float)x0;
        float yd = y - (float)y0;
        float zd = z - (float)z0;

        int xl = x0 - X0, yl = y0 - Y0, zl = z0 - Z0;   // 0..7
        float4 c000 = sv[SIDX(xl,     yl,     zl    )];
        float4 c001 = sv[SIDX(xl,     yl,     zl + 1)];
        float4 c010 = sv[SIDX(xl,     yl + 1, zl    )];
        float4 c011 = sv[SIDX(xl,     yl + 1, zl + 1)];
        float4 c100 = sv[SIDX(xl + 1, yl,     zl    )];
        float4 c101 = sv[SIDX(xl + 1, yl,     zl + 1)];
        float4 c110 = sv[SIDX(xl + 1, yl + 1, zl    )];
        float4 c111 = sv[SIDX(xl + 1, yl + 1, zl + 1)];

        float4 c00 = lerp4(c000, c100, xd);
        float4 c01 = lerp4(c001, c101, xd);
        float4 c10 = lerp4(c010, c110, xd);
        float4 c11 = lerp4(c011, c111, xd);
        float4 c0  = lerp4(c00, c10, yd);
        float4 c1  = lerp4(c01, c11, yd);
        float4 res = lerp4(c0, c1, zd);

        unsigned idx = __float_as_uint(r.w);
        __builtin_nontemporal_store(*(fvec4*)&res, (fvec4*)(out + ((size_t)idx * 4 + c4)));
    }
    #undef SIDX
}

// ---------------- Tier-2 fallback: single-level direct scatter (v2-style) ----------------
__global__ __launch_bounds__(256) void direct_scatter(
    const float* __restrict__ points,
    unsigned* __restrict__ fcur,
    float4* __restrict__ frecs,
    const float4* __restrict__ values,
    float4* __restrict__ out,
    int n_points)
{
    int p = blockIdx.x * blockDim.x + threadIdx.x;
    if (p >= n_points) return;
    float x = points[p * 3 + 0] * 20.0f;
    float y = points[p * 3 + 1] * 20.0f;
    float z = points[p * 3 + 2] * 20.0f;
    int fx = clampi((int)floorf(x), 0, DD - 1) >> 3;
    int fy = clampi((int)floorf(y), 0, DD - 1) >> 3;
    int fz = clampi((int)floorf(z), 0, DD - 1) >> 3;
    int fb = (fx * NBX + fy) * NBX + fz;
    unsigned pos = atomicAdd(&fcur[fb * FCUR_STRIDE], 1u);
    if (pos < CAPF) {
        fvec4 r = { x, y, z, __uint_as_float((unsigned)p) };
        __builtin_nontemporal_store(r, (fvec4*)(frecs + (size_t)fb * CAPF + pos));
    } else {
        write_point_direct(values, out, x, y, z, (unsigned)p);
    }
}

// ---------------- Tier-3 fallback: v1 direct kernel ----------------
__global__ __launch_bounds__(256) void trilerp_kernel(
    const float* __restrict__ points,
    const float4* __restrict__ values,
    float4* __restrict__ out,
    int n_points)
{
    int t = blockIdx.x * blockDim.x + threadIdx.x;
    int p = t >> 2;
    int c4 = t & 3;
    if (p >= n_points) return;
    float x = points[p * 3 + 0] * 20.0f;
    float y = points[p * 3 + 1] * 20.0f;
    float z = points[p * 3 + 2] * 20.0f;
    out[t] = trilerp_point(values, x, y, z, c4);
}

extern "C" void kernel_launch(void* const* d_in, const int* in_sizes, int n_in,
                              void* d_out, int out_size, void* d_ws, size_t ws_size,
                              hipStream_t stream) {
    const float* points = (const float*)d_in[0];
    const float4* values = (const float4*)d_in[1];
    float4* out = (float4*)d_out;
    int n_points = in_sizes[0] / 3;

    const size_t ccur_b  = (size_t)NC * CCUR_STRIDE * sizeof(unsigned);     // 4 KB
    const size_t fcur_b  = (size_t)NB * FCUR_STRIDE * sizeof(unsigned);     // 64 KB
    const size_t crecs_b = (size_t)NC * CAPC * sizeof(float4);              // ~33.8 MB
    const size_t frecs_b = (size_t)NB * CAPF * sizeof(float4);              // ~36.7 MB

    if (d_ws != nullptr && ws_size >= ccur_b + fcur_b + crecs_b + frecs_b) {
        // Tier 1: hierarchical binning.
        unsigned* ccur  = (unsigned*)d_ws;
        unsigned* fcur  = (unsigned*)((char*)d_ws + ccur_b);
        float4*   crecs = (float4*)((char*)d_ws + ccur_b + fcur_b);
        float4*   frecs = (float4*)((char*)d_ws + ccur_b + fcur_b + crecs_b);

        hipMemsetAsync(d_ws, 0, ccur_b + fcur_b, stream);
        coarse_scatter<<<SCAT_BLOCKS, 256, 0, stream>>>(points, ccur, crecs, values, out, n_points);
        fine_scatter<<<NC * 8, 256, 0, stream>>>(crecs, ccur, fcur, frecs, values, out);
        interp_kernel<<<NB, 256, 0, stream>>>(frecs, fcur, values, out);
    } else if (d_ws != nullptr && ws_size >= fcur_b + frecs_b) {
        // Tier 2: single-level scatter (slower, proven).
        unsigned* fcur  = (unsigned*)d_ws;
        float4*   frecs = (float4*)((char*)d_ws + fcur_b);

        hipMemsetAsync(d_ws, 0, fcur_b, stream);
        int blocks = (n_points + 255) / 256;
        direct_scatter<<<blocks, 256, 0, stream>>>(points, fcur, frecs, values, out, n_points);
        interp_kernel<<<NB, 256, 0, stream>>>(frecs, fcur, values, out);
    } else {
        // Tier 3: original direct kernel.
        int total_threads = n_points * 4;
        int blocks = (total_threads + 255) / 256;
        trilerp_kernel<<<blocks, 256, 0, stream>>>(points, values, out, n_points);
    }
}